// Round 1
// baseline (203.558 us; speedup 1.0000x reference)
//
#include <hip/hip_runtime.h>

// Problem geometry
#define TOT   19267584   // 128*768*14*14 == 128*3*224*224
#define MROWS 25088      // 128*196 patches
#define KD    768        // 3*16*16
#define ND    768        // out channels
#define NPB   196        // 14*14 patches per image
#define CHW   150528     // 768*196 (per-image output block)

typedef unsigned int uint;
typedef __attribute__((ext_vector_type(4))) float f32x4;
typedef __attribute__((ext_vector_type(8))) short s16x8;

// workspace layout (bytes)
#define OFF_AQ   0ull              // ushort A_q[MROWS*KD] = 38,535,168 B ; aliased later: int8 k1[TOT]
#define OFF_WQ   38535168ull       // ushort w_int[ND*KD] = 1,179,648 B
#define OFF_WSC  39714816ull       // float w_scale[768]
#define OFF_INV  39717888ull       // float inv[768]
#define OFF_SHF  39720960ull       // float shift[768]
#define OFF_SC   39724032ull       // uint scalars[4]: max|x|, max|y_conv|, max|y2|, max|y4|

__device__ __forceinline__ float wave_max(float v) {
#pragma unroll
  for (int off = 32; off > 0; off >>= 1) v = fmaxf(v, __shfl_xor(v, off));
  return v;
}

__device__ __forceinline__ void block_max_atomic(float v, uint* dst) {
  __shared__ float red[4];
  v = wave_max(v);
  const int lane = threadIdx.x & 63, wv = threadIdx.x >> 6;
  if (lane == 0) red[wv] = v;
  __syncthreads();
  if (threadIdx.x == 0)
    atomicMax(dst, __float_as_uint(fmaxf(fmaxf(red[0], red[1]), fmaxf(red[2], red[3]))));
}

// ---------------- K0: global max|x| ----------------
__global__ void k_maxabs(const float* __restrict__ x, uint* __restrict__ sc) {
  float m = 0.f;
  const float4* x4 = (const float4*)x;
  for (int i = blockIdx.x * blockDim.x + threadIdx.x; i < TOT / 4; i += gridDim.x * blockDim.x) {
    float4 v = x4[i];
    m = fmaxf(m, fmaxf(fmaxf(fabsf(v.x), fabsf(v.y)), fmaxf(fabsf(v.z), fabsf(v.w))));
  }
  block_max_atomic(m, sc + 0);
}

// ---------------- K1: weight quant (per-oc) + BN coefficients ----------------
__global__ void k_wquant(const float* __restrict__ W, const float* __restrict__ gamma,
                         const float* __restrict__ beta, const float* __restrict__ rmean,
                         const float* __restrict__ rvar, unsigned short* __restrict__ wq,
                         float* __restrict__ wscale, float* __restrict__ inv_,
                         float* __restrict__ shf) {
  const int oc = blockIdx.x;
  const float* row = W + oc * KD;
  float m = 0.f;
  for (int k = threadIdx.x; k < KD; k += 256) m = fmaxf(m, fabsf(row[k]));
  __shared__ float red[4];
  m = wave_max(m);
  if ((threadIdx.x & 63) == 0) red[threadIdx.x >> 6] = m;
  __syncthreads();
  const float ws_ = fmaxf(fmaxf(red[0], red[1]), fmaxf(red[2], red[3])) / 127.0f;
  for (int k = threadIdx.x; k < KD; k += 256) {
    float q = rintf(row[k] / ws_);                       // integer in [-127,127]
    wq[oc * KD + k] = (unsigned short)(__float_as_uint(q) >> 16);  // exact bf16 (int <= 127)
  }
  if (threadIdx.x == 0) {
    wscale[oc] = ws_;
    float iv = gamma[oc] / sqrtf(rvar[oc] + 1e-5f);
    inv_[oc] = iv;
    shf[oc] = __fsub_rn(beta[oc], __fmul_rn(rmean[oc], iv));  // match jax: mul then sub, no fma
  }
}

// ---------------- K2: im2col + activation quant -> bf16 A_q[MROWS][KD] ----------------
__device__ __forceinline__ unsigned short q8(float v, float s) {
  float q = fminf(fmaxf(rintf(v / s), -127.f), 127.f);
  return (unsigned short)(__float_as_uint(q) >> 16);     // exact bf16
}

__global__ void k_im2col(const float* __restrict__ x, const uint* __restrict__ sc,
                         unsigned short* __restrict__ aq) {
  const float ps = __uint_as_float(sc[0]) / 127.0f;
  for (int u = blockIdx.x * blockDim.x + threadIdx.x; u < TOT / 4; u += gridDim.x * blockDim.x) {
    int p = u / 192;                // patch index
    int k = (u - p * 192) * 4;      // k index (multiple of 4)
    int c = k >> 8;
    int r = k & 255;
    int kh = r >> 4, kw = r & 15;
    int b = p / NPB;
    int pp = p - b * NPB;
    int ph = pp / 14;
    int pw = pp - ph * 14;
    float4 v = *(const float4*)(x + (((b * 3 + c) * 224 + ph * 16 + kh) * 224 + pw * 16 + kw));
    ushort4 o;
    o.x = q8(v.x, ps); o.y = q8(v.y, ps); o.z = q8(v.z, ps); o.w = q8(v.w, ps);
    *(ushort4*)(aq + (size_t)p * KD + k) = o;
  }
}

// ---------------- K3: bf16 MFMA GEMM (exact integer), epilogue scale+bias+max ----------------
__device__ __forceinline__ void gl_lds16(const void* g, void* l) {
  __builtin_amdgcn_global_load_lds((const __attribute__((address_space(1))) void*)g,
                                   (__attribute__((address_space(3))) void*)l, 16, 0, 0);
}

__global__ __launch_bounds__(256) void k_gemm(const unsigned short* __restrict__ aq,
                                              const unsigned short* __restrict__ wq,
                                              const float* __restrict__ bias,
                                              const float* __restrict__ wscale,
                                              uint* __restrict__ sc,
                                              float* __restrict__ y) {
  __shared__ short lA[128 * 32];
  __shared__ short lB[128 * 32];
  const int tid = threadIdx.x, lane = tid & 63, wv = tid >> 6;
  const int bm = blockIdx.x % 196, bn = blockIdx.x / 196;
  const int wr = wv >> 1, wc = wv & 1;                   // 2x2 waves, 64x64 each
  const float ps = __uint_as_float(sc[0]) / 127.0f;

  // staging: 8192B tile per matrix = 8 wave-chunks of 1024B (global_load_lds width 16)
  const int o0 = (wv * 2 + 0) * 1024 + lane * 16;
  const int o1 = (wv * 2 + 1) * 1024 + lane * 16;
  const int r0 = o0 >> 6, k0e = (o0 & 63) >> 1;
  const int r1 = o1 >> 6, k1e = (o1 & 63) >> 1;
  const unsigned short* gA0 = aq + (size_t)(bm * 128 + r0) * KD + k0e;
  const unsigned short* gA1 = aq + (size_t)(bm * 128 + r1) * KD + k1e;
  const unsigned short* gB0 = wq + (size_t)(bn * 128 + r0) * KD + k0e;
  const unsigned short* gB1 = wq + (size_t)(bn * 128 + r1) * KD + k1e;
  char* dA0 = (char*)lA + (wv * 2 + 0) * 1024;
  char* dA1 = (char*)lA + (wv * 2 + 1) * 1024;
  char* dB0 = (char*)lB + (wv * 2 + 0) * 1024;
  char* dB1 = (char*)lB + (wv * 2 + 1) * 1024;

  f32x4 acc[4][4];
#pragma unroll
  for (int m = 0; m < 4; ++m)
#pragma unroll
    for (int n = 0; n < 4; ++n) acc[m][n] = (f32x4){0.f, 0.f, 0.f, 0.f};

  const int rbase = lane & 15;
  const int kg = (lane >> 4) * 8;

  for (int kk = 0; kk < KD; kk += 32) {
    __syncthreads();
    gl_lds16(gA0 + kk, dA0);
    gl_lds16(gA1 + kk, dA1);
    gl_lds16(gB0 + kk, dB0);
    gl_lds16(gB1 + kk, dB1);
    __syncthreads();  // compiler drains vmcnt before barrier -> tile visible
    s16x8 af[4], bf[4];
#pragma unroll
    for (int m = 0; m < 4; ++m)
      af[m] = *(const s16x8*)&lA[(wr * 64 + m * 16 + rbase) * 32 + kg];
#pragma unroll
    for (int n = 0; n < 4; ++n)
      bf[n] = *(const s16x8*)&lB[(wc * 64 + n * 16 + rbase) * 32 + kg];
#pragma unroll
    for (int m = 0; m < 4; ++m)
#pragma unroll
      for (int n = 0; n < 4; ++n)
        acc[m][n] = __builtin_amdgcn_mfma_f32_16x16x32_bf16(af[m], bf[n], acc[m][n], 0, 0, 0);
  }

  // epilogue: y = (acc + b_int) * comb_s, write in final [B,768,14,14] layout
  float lmax = 0.f;
  const int prow = (lane >> 4) << 2;
#pragma unroll
  for (int n = 0; n < 4; ++n) {
    const int oc = bn * 128 + wc * 64 + n * 16 + rbase;
    const float comb = wscale[oc] * ps;
    const float bint = rintf(bias[oc] / comb);
#pragma unroll
    for (int m = 0; m < 4; ++m) {
      const int p0 = bm * 128 + wr * 64 + m * 16 + prow;  // 4-aligned; q+3 < 196 guaranteed
      const int img = p0 / 196;
      const int q = p0 - img * 196;
      float4 o;
      o.x = (acc[m][n][0] + bint) * comb;
      o.y = (acc[m][n][1] + bint) * comb;
      o.z = (acc[m][n][2] + bint) * comb;
      o.w = (acc[m][n][3] + bint) * comb;
      lmax = fmaxf(lmax, fmaxf(fmaxf(fabsf(o.x), fabsf(o.y)), fmaxf(fabsf(o.z), fabsf(o.w))));
      *(float4*)(y + (size_t)img * CHW + (size_t)oc * 196 + q) = o;
    }
  }
  block_max_atomic(lmax, sc + 1);
}

// ---------------- K4: k1 = quant(y_conv); max|gelu(k1*s1)| via 255-LUT ----------------
__global__ void k_gelu(const float* __restrict__ ycv, const uint* __restrict__ sc,
                       signed char* __restrict__ k1, uint* __restrict__ scw) {
  __shared__ float tabs[255];
  const float s1 = __uint_as_float(sc[1]) / 127.0f;
  for (int t = threadIdx.x; t < 255; t += 256) {
    float y1 = (float)(t - 127) * s1;
    float e = erff(y1 / 1.41421356237309505f);
    tabs[t] = fabsf((y1 * (e + 1.0f)) * 0.5f);   // |gelu|, jax op order: x*(erf+1)/2
  }
  __syncthreads();
  float m = 0.f;
  for (int u = blockIdx.x * blockDim.x + threadIdx.x; u < TOT / 4; u += gridDim.x * blockDim.x) {
    float4 v = ((const float4*)ycv)[u];
    int a = (int)fminf(fmaxf(rintf(v.x / s1), -127.f), 127.f);
    int b = (int)fminf(fmaxf(rintf(v.y / s1), -127.f), 127.f);
    int c = (int)fminf(fmaxf(rintf(v.z / s1), -127.f), 127.f);
    int d = (int)fminf(fmaxf(rintf(v.w / s1), -127.f), 127.f);
    char4 kk;
    kk.x = (signed char)a; kk.y = (signed char)b; kk.z = (signed char)c; kk.w = (signed char)d;
    m = fmaxf(m, fmaxf(fmaxf(tabs[a + 127], tabs[b + 127]), fmaxf(tabs[c + 127], tabs[d + 127])));
    ((char4*)k1)[u] = kk;
  }
  block_max_atomic(m, scw);
}

// ---------------- K5: max|BN(quant(gelu))| via LUT ----------------
__global__ void k_bnmax(const signed char* __restrict__ k1, const uint* __restrict__ sc,
                        const float* __restrict__ inv_, const float* __restrict__ shf,
                        uint* __restrict__ scw) {
  __shared__ float tab[255];  // y3 = k2*s2 as function of k1
  const float s1 = __uint_as_float(sc[1]) / 127.0f;
  const float s2 = __uint_as_float(sc[2]) / 127.0f;
  for (int t = threadIdx.x; t < 255; t += 256) {
    float y1 = (float)(t - 127) * s1;
    float e = erff(y1 / 1.41421356237309505f);
    float y2 = (y1 * (e + 1.0f)) * 0.5f;
    float q2 = fminf(fmaxf(rintf(y2 / s2), -127.f), 127.f);
    tab[t] = q2 * s2;
  }
  __syncthreads();
  float m = 0.f;
  for (int u = blockIdx.x * blockDim.x + threadIdx.x; u < TOT / 4; u += gridDim.x * blockDim.x) {
    int c = ((u * 4) / 196) % 768;          // 196%4==0 -> whole char4 shares channel
    float iv = inv_[c], sh = shf[c];
    char4 kk = ((const char4*)k1)[u];
    float a = __fadd_rn(__fmul_rn(tab[kk.x + 127], iv), sh);
    float b = __fadd_rn(__fmul_rn(tab[kk.y + 127], iv), sh);
    float cc = __fadd_rn(__fmul_rn(tab[kk.z + 127], iv), sh);
    float d = __fadd_rn(__fmul_rn(tab[kk.w + 127], iv), sh);
    m = fmaxf(m, fmaxf(fmaxf(fabsf(a), fabsf(b)), fmaxf(fabsf(cc), fabsf(d))));
  }
  block_max_atomic(m, scw);
}

// ---------------- K6: final quant-dequant write + act_scale ----------------
__global__ void k_final(const signed char* __restrict__ k1, const uint* __restrict__ sc,
                        const float* __restrict__ inv_, const float* __restrict__ shf,
                        float* __restrict__ out) {
  __shared__ float tab[255];
  const float s1 = __uint_as_float(sc[1]) / 127.0f;
  const float s2 = __uint_as_float(sc[2]) / 127.0f;
  const float s3 = __uint_as_float(sc[3]) / 127.0f;
  for (int t = threadIdx.x; t < 255; t += 256) {
    float y1 = (float)(t - 127) * s1;
    float e = erff(y1 / 1.41421356237309505f);
    float y2 = (y1 * (e + 1.0f)) * 0.5f;
    float q2 = fminf(fmaxf(rintf(y2 / s2), -127.f), 127.f);
    tab[t] = q2 * s2;
  }
  __syncthreads();
  for (int u = blockIdx.x * blockDim.x + threadIdx.x; u < TOT / 4; u += gridDim.x * blockDim.x) {
    int c = ((u * 4) / 196) % 768;
    float iv = inv_[c], sh = shf[c];
    char4 kk = ((const char4*)k1)[u];
    float4 o;
    float a = __fadd_rn(__fmul_rn(tab[kk.x + 127], iv), sh);
    float b = __fadd_rn(__fmul_rn(tab[kk.y + 127], iv), sh);
    float cc = __fadd_rn(__fmul_rn(tab[kk.z + 127], iv), sh);
    float d = __fadd_rn(__fmul_rn(tab[kk.w + 127], iv), sh);
    o.x = fminf(fmaxf(rintf(a / s3), -127.f), 127.f) * s3;
    o.y = fminf(fmaxf(rintf(b / s3), -127.f), 127.f) * s3;
    o.z = fminf(fmaxf(rintf(cc / s3), -127.f), 127.f) * s3;
    o.w = fminf(fmaxf(rintf(d / s3), -127.f), 127.f) * s3;
    ((float4*)out)[u] = o;
  }
  if (blockIdx.x == 0 && threadIdx.x == 0) out[TOT] = s3;  // act_scale
}

extern "C" void kernel_launch(void* const* d_in, const int* in_sizes, int n_in,
                              void* d_out, int out_size, void* d_ws, size_t ws_size,
                              hipStream_t stream) {
  const float* x     = (const float*)d_in[0];
  const float* W     = (const float*)d_in[1];
  const float* bias  = (const float*)d_in[2];
  const float* gamma = (const float*)d_in[3];
  const float* beta  = (const float*)d_in[4];
  const float* rmean = (const float*)d_in[5];
  const float* rvar  = (const float*)d_in[6];
  float* out = (float*)d_out;
  char* ws = (char*)d_ws;

  unsigned short* aq  = (unsigned short*)(ws + OFF_AQ);
  unsigned short* wq  = (unsigned short*)(ws + OFF_WQ);
  float* wsc  = (float*)(ws + OFF_WSC);
  float* inv_ = (float*)(ws + OFF_INV);
  float* shf  = (float*)(ws + OFF_SHF);
  uint*  sc   = (uint*)(ws + OFF_SC);
  signed char* k1 = (signed char*)(ws + OFF_AQ);  // aliases aq (dead after GEMM)

  hipMemsetAsync(sc, 0, 16, stream);
  k_maxabs<<<2048, 256, 0, stream>>>(x, sc);
  k_wquant<<<768, 256, 0, stream>>>(W, gamma, beta, rmean, rvar, wq, wsc, inv_, shf);
  k_im2col<<<2048, 256, 0, stream>>>(x, sc, aq);
  k_gemm<<<196 * 6, 256, 0, stream>>>(aq, wq, bias, wsc, sc, out);
  k_gelu<<<2048, 256, 0, stream>>>(out, sc, k1, sc + 2);
  k_bnmax<<<1536, 256, 0, stream>>>(k1, sc, inv_, shf, sc + 3);
  k_final<<<2048, 256, 0, stream>>>(k1, sc, inv_, shf, out);
}

// Round 2
// 154.596 us; speedup vs baseline: 1.3167x; 1.3167x over previous
//
#include <hip/hip_runtime.h>

// Problem geometry
#define TOT   19267584   // 128*768*14*14 == 128*3*224*224
#define MROWS 25088      // 128*196 patches
#define KD    768        // 3*16*16
#define NPB   196
#define CHW   150528     // 768*196

typedef unsigned int uint;
typedef __attribute__((ext_vector_type(4))) int i32x4;

// workspace layout (bytes)
#define OFF_AQ   0ull              // int8 aq[25088*768] = 19,267,584 ; aliased later: int8 k1[TOT]
#define OFF_WQ   19267584ull       // int8 wq[768*768] = 589,824
#define OFF_WSC  19857408ull       // float w_scale[768]
#define OFF_INV  19860480ull       // float inv[768]
#define OFF_SHF  19863552ull       // float shift[768]
#define OFF_CMN  19866624ull       // float chmin[768]
#define OFF_CMX  19869696ull       // float chmax[768]
#define OFF_SC   19872768ull       // uint sc[4]: max|x| bits, max|y_conv| bits, s2 bits, s3 bits

__device__ __forceinline__ float wave_max(float v) {
#pragma unroll
  for (int off = 32; off > 0; off >>= 1) v = fmaxf(v, __shfl_xor(v, off));
  return v;
}

__device__ __forceinline__ void block_max_atomic(float v, uint* dst) {
  __shared__ float red[4];
  v = wave_max(v);
  const int lane = threadIdx.x & 63, wv = threadIdx.x >> 6;
  if (lane == 0) red[wv] = v;
  __syncthreads();
  if (threadIdx.x == 0)
    atomicMax(dst, __float_as_uint(fmaxf(fmaxf(red[0], red[1]), fmaxf(red[2], red[3]))));
}

// ---------------- K0: global max|x| ----------------
__global__ void k_maxabs(const float* __restrict__ x, uint* __restrict__ sc) {
  float m = 0.f;
  const float4* x4 = (const float4*)x;
  for (int i = blockIdx.x * blockDim.x + threadIdx.x; i < TOT / 4; i += gridDim.x * blockDim.x) {
    float4 v = x4[i];
    m = fmaxf(m, fmaxf(fmaxf(fabsf(v.x), fabsf(v.y)), fmaxf(fabsf(v.z), fabsf(v.w))));
  }
  block_max_atomic(m, sc + 0);
}

// ---------------- K1: weight quant (per-oc, int8) + BN coefficients ----------------
__global__ void k_wquant(const float* __restrict__ W, const float* __restrict__ gamma,
                         const float* __restrict__ beta, const float* __restrict__ rmean,
                         const float* __restrict__ rvar, signed char* __restrict__ wq,
                         float* __restrict__ wscale, float* __restrict__ inv_,
                         float* __restrict__ shf) {
  const int oc = blockIdx.x;
  const float* row = W + oc * KD;
  float m = 0.f;
  for (int k = threadIdx.x; k < KD; k += 256) m = fmaxf(m, fabsf(row[k]));
  __shared__ float red[4];
  m = wave_max(m);
  if ((threadIdx.x & 63) == 0) red[threadIdx.x >> 6] = m;
  __syncthreads();
  const float ws_ = fmaxf(fmaxf(red[0], red[1]), fmaxf(red[2], red[3])) / 127.0f;
  for (int k = threadIdx.x; k < KD; k += 256)
    wq[oc * KD + k] = (signed char)(int)rintf(row[k] / ws_);
  if (threadIdx.x == 0) {
    wscale[oc] = ws_;
    float iv = gamma[oc] / sqrtf(rvar[oc] + 1e-5f);
    inv_[oc] = iv;
    shf[oc] = __fsub_rn(beta[oc], __fmul_rn(rmean[oc], iv));  // jax: mul then sub, no fma
  }
}

// ---------------- K2: im2col + activation quant -> int8 A_q[MROWS][KD] ----------------
__global__ void k_im2col(const float* __restrict__ x, const uint* __restrict__ sc,
                         signed char* __restrict__ aq) {
  const float ps = __uint_as_float(sc[0]) / 127.0f;
  char4* a4 = (char4*)aq;
  for (int u = blockIdx.x * blockDim.x + threadIdx.x; u < TOT / 4; u += gridDim.x * blockDim.x) {
    int p = u / 192;                // patch index
    int k = (u - p * 192) * 4;      // k index (multiple of 4)
    int c = k >> 8;
    int r = k & 255;
    int kh = r >> 4, kw = r & 15;
    int b = p / NPB;
    int pp = p - b * NPB;
    int ph = pp / 14;
    int pw = pp - ph * 14;
    float4 v = *(const float4*)(x + (((b * 3 + c) * 224 + ph * 16 + kh) * 224 + pw * 16 + kw));
    char4 o;
    o.x = (signed char)(int)fminf(fmaxf(rintf(v.x / ps), -127.f), 127.f);
    o.y = (signed char)(int)fminf(fmaxf(rintf(v.y / ps), -127.f), 127.f);
    o.z = (signed char)(int)fminf(fmaxf(rintf(v.z / ps), -127.f), 127.f);
    o.w = (signed char)(int)fminf(fmaxf(rintf(v.w / ps), -127.f), 127.f);
    a4[u] = o;
  }
}

// ---------------- K3: i8 MFMA GEMM, 2-phase dbuf, epilogue scale+bias+max ----------------
__device__ __forceinline__ void gl_lds16(const void* g, void* l) {
  __builtin_amdgcn_global_load_lds((const __attribute__((address_space(1))) void*)g,
                                   (__attribute__((address_space(3))) void*)l, 16, 0, 0);
}

__global__ __launch_bounds__(256) void k_gemm(const signed char* __restrict__ aq,
                                              const signed char* __restrict__ wq,
                                              const float* __restrict__ bias,
                                              const float* __restrict__ wscale,
                                              uint* __restrict__ sc,
                                              float* __restrict__ y) {
  __shared__ __align__(16) signed char lA[2][8192];   // 128 rows x 64 K (i8), dbuf
  __shared__ __align__(16) signed char lB[2][8192];
  const int tid = threadIdx.x, lane = tid & 63, wv = tid >> 6;
  // XCD-aware swizzle (1176 = 8*147, bijective) + bn-inner for A-tile L2 reuse
  const int bsw = (blockIdx.x & 7) * 147 + (blockIdx.x >> 3);
  const int bm = bsw / 6, bn = bsw - 6 * (bsw / 6);
  const int wr = wv >> 1, wc = wv & 1;               // 2x2 waves, 64x64 each
  const float ps = __uint_as_float(sc[0]) / 127.0f;

  // staging: 8192B tile = 8 chunks of 1024B (16 rows of 64B); each wave does 2 chunks/matrix
  const int ci0 = wv * 2, ci1 = wv * 2 + 1;
  const int rr0 = ci0 * 16 + (lane >> 2);
  const int rr1 = ci1 * 16 + (lane >> 2);
  const int bo = (lane & 3) * 16;
  const signed char* gA0 = aq + (size_t)(bm * 128 + rr0) * KD + bo;
  const signed char* gA1 = aq + (size_t)(bm * 128 + rr1) * KD + bo;
  const signed char* gB0 = wq + (size_t)(bn * 128 + rr0) * KD + bo;
  const signed char* gB1 = wq + (size_t)(bn * 128 + rr1) * KD + bo;

  i32x4 acc[4][4];
#pragma unroll
  for (int m = 0; m < 4; ++m)
#pragma unroll
    for (int n = 0; n < 4; ++n) acc[m][n] = (i32x4){0, 0, 0, 0};

  const int rbase = lane & 15;
  const int kg = (lane >> 4) * 16;   // byte offset into 64B row (16 i8 = K-slice)

  // prologue: stage tile 0
  gl_lds16(gA0, &lA[0][ci0 * 1024]);
  gl_lds16(gA1, &lA[0][ci1 * 1024]);
  gl_lds16(gB0, &lB[0][ci0 * 1024]);
  gl_lds16(gB1, &lB[0][ci1 * 1024]);
  __syncthreads();

  int cur = 0;
  for (int t = 0; t < 12; ++t) {
    if (t < 11) {                                    // prefetch next K-tile into other buffer
      const int kk = (t + 1) * 64;
      gl_lds16(gA0 + kk, &lA[cur ^ 1][ci0 * 1024]);
      gl_lds16(gA1 + kk, &lA[cur ^ 1][ci1 * 1024]);
      gl_lds16(gB0 + kk, &lB[cur ^ 1][ci0 * 1024]);
      gl_lds16(gB1 + kk, &lB[cur ^ 1][ci1 * 1024]);
    }
    i32x4 af[4], bfr[4];
#pragma unroll
    for (int m = 0; m < 4; ++m)
      af[m] = *(const i32x4*)&lA[cur][(wr * 64 + m * 16 + rbase) * 64 + kg];
#pragma unroll
    for (int n = 0; n < 4; ++n)
      bfr[n] = *(const i32x4*)&lB[cur][(wc * 64 + n * 16 + rbase) * 64 + kg];
#pragma unroll
    for (int m = 0; m < 4; ++m)
#pragma unroll
      for (int n = 0; n < 4; ++n)
        acc[m][n] = __builtin_amdgcn_mfma_i32_16x16x64_i8(af[m], bfr[n], acc[m][n], 0, 0, 0);
    __syncthreads();   // drains vmcnt (prefetch landed) + lgkm; buffers swap safely
    cur ^= 1;
  }

  // epilogue: y = (acc + b_int) * comb_s, final [B,768,14,14] layout
  float lmax = 0.f;
  const int prow = (lane >> 4) << 2;
#pragma unroll
  for (int n = 0; n < 4; ++n) {
    const int oc = bn * 128 + wc * 64 + n * 16 + rbase;
    const float comb = wscale[oc] * ps;
    const float bint = rintf(bias[oc] / comb);
#pragma unroll
    for (int m = 0; m < 4; ++m) {
      const int p0 = bm * 128 + wr * 64 + m * 16 + prow;  // 4-aligned; stays within one image
      const int img = p0 / 196;
      const int q = p0 - img * 196;
      float4 o;
      o.x = ((float)acc[m][n][0] + bint) * comb;
      o.y = ((float)acc[m][n][1] + bint) * comb;
      o.z = ((float)acc[m][n][2] + bint) * comb;
      o.w = ((float)acc[m][n][3] + bint) * comb;
      lmax = fmaxf(lmax, fmaxf(fmaxf(fabsf(o.x), fabsf(o.y)), fmaxf(fabsf(o.z), fabsf(o.w))));
      *(float4*)(y + (size_t)img * CHW + (size_t)oc * 196 + q) = o;
    }
  }
  block_max_atomic(lmax, sc + 1);
}

// ---------------- K4: per-channel gelu pass: write k1, per-channel min/max of y2 ----------------
__global__ void k_gelu_chan(const float* __restrict__ y, const uint* __restrict__ sc,
                            signed char* __restrict__ k1, float* __restrict__ chmn,
                            float* __restrict__ chmx) {
  const int c = blockIdx.x;           // one block per channel
  const float s1 = __uint_as_float(sc[1]) / 127.0f;
  __shared__ float tab[255];          // gelu(k*s1), signed
  for (int t = threadIdx.x; t < 255; t += 256) {
    float y1 = (float)(t - 127) * s1;
    float e = erff(y1 * 0.70710678118654752f);
    tab[t] = (y1 * (e + 1.0f)) * 0.5f;
  }
  __syncthreads();
  float mn = 1e30f, mx = -1e30f;
  char4* k4 = (char4*)k1;
  for (int u = threadIdx.x; u < 6272; u += 256) {   // 128 imgs * 49 float4
    int img = u / 49, j = u - img * 49;
    size_t base4 = (size_t)img * (CHW / 4) + c * 49;
    float4 v = ((const float4*)y)[base4 + j];
    int a = (int)fminf(fmaxf(rintf(v.x / s1), -127.f), 127.f);
    int b = (int)fminf(fmaxf(rintf(v.y / s1), -127.f), 127.f);
    int cc = (int)fminf(fmaxf(rintf(v.z / s1), -127.f), 127.f);
    int d = (int)fminf(fmaxf(rintf(v.w / s1), -127.f), 127.f);
    char4 kk;
    kk.x = (signed char)a; kk.y = (signed char)b; kk.z = (signed char)cc; kk.w = (signed char)d;
    k4[base4 + j] = kk;
    float ga = tab[a + 127], gb = tab[b + 127], gc = tab[cc + 127], gd = tab[d + 127];
    mn = fminf(mn, fminf(fminf(ga, gb), fminf(gc, gd)));
    mx = fmaxf(mx, fmaxf(fmaxf(ga, gb), fmaxf(gc, gd)));
  }
  __shared__ float rmn[4], rmx[4];
#pragma unroll
  for (int off = 32; off > 0; off >>= 1) {
    mn = fminf(mn, __shfl_xor(mn, off));
    mx = fmaxf(mx, __shfl_xor(mx, off));
  }
  const int lane = threadIdx.x & 63, wv = threadIdx.x >> 6;
  if (lane == 0) { rmn[wv] = mn; rmx[wv] = mx; }
  __syncthreads();
  if (threadIdx.x == 0) {
    chmn[c] = fminf(fminf(rmn[0], rmn[1]), fminf(rmn[2], rmn[3]));
    chmx[c] = fmaxf(fmaxf(rmx[0], rmx[1]), fmaxf(rmx[2], rmx[3]));
  }
}

// ---------------- K5: scales from channel extremes (monotone chain => exact) ----------------
__global__ void k_scales(const float* __restrict__ chmn, const float* __restrict__ chmx,
                         const float* __restrict__ inv_, const float* __restrict__ shf,
                         uint* __restrict__ sc) {
  __shared__ float sred[4];
  __shared__ float s2sh;
  const int tid = threadIdx.x;
  float m2 = 0.f;
  for (int c = tid; c < 768; c += 256)
    m2 = fmaxf(m2, fmaxf(fabsf(chmn[c]), fabsf(chmx[c])));
  m2 = wave_max(m2);
  if ((tid & 63) == 0) sred[tid >> 6] = m2;
  __syncthreads();
  if (tid == 0) {
    float s2 = fmaxf(fmaxf(sred[0], sred[1]), fmaxf(sred[2], sred[3])) / 127.0f;
    s2sh = s2;
    sc[2] = __float_as_uint(s2);
  }
  __syncthreads();
  const float s2 = s2sh;
  float m4 = 0.f;
  for (int c = tid; c < 768; c += 256) {
    float iv = inv_[c], sh = shf[c];
    float a = fminf(fmaxf(rintf(chmn[c] / s2), -127.f), 127.f) * s2;
    float b = fminf(fmaxf(rintf(chmx[c] / s2), -127.f), 127.f) * s2;
    float ya = __fadd_rn(__fmul_rn(a, iv), sh);
    float yb = __fadd_rn(__fmul_rn(b, iv), sh);
    m4 = fmaxf(m4, fmaxf(fabsf(ya), fabsf(yb)));
  }
  m4 = wave_max(m4);
  __syncthreads();
  if ((tid & 63) == 0) sred[tid >> 6] = m4;
  __syncthreads();
  if (tid == 0)
    sc[3] = __float_as_uint(fmaxf(fmaxf(sred[0], sred[1]), fmaxf(sred[2], sred[3])) / 127.0f);
}

// ---------------- K6: final quant-dequant write + act_scale ----------------
__global__ void k_final(const signed char* __restrict__ k1, const uint* __restrict__ sc,
                        const float* __restrict__ inv_, const float* __restrict__ shf,
                        float* __restrict__ out) {
  __shared__ float tab[255];
  const float s1 = __uint_as_float(sc[1]) / 127.0f;
  const float s2 = __uint_as_float(sc[2]);
  const float s3 = __uint_as_float(sc[3]);
  for (int t = threadIdx.x; t < 255; t += 256) {
    float y1 = (float)(t - 127) * s1;
    float e = erff(y1 * 0.70710678118654752f);
    float y2 = (y1 * (e + 1.0f)) * 0.5f;
    float q2 = fminf(fmaxf(rintf(y2 / s2), -127.f), 127.f);
    tab[t] = q2 * s2;
  }
  __syncthreads();
  for (int u = blockIdx.x * blockDim.x + threadIdx.x; u < TOT / 4; u += gridDim.x * blockDim.x) {
    int c = ((u * 4) / 196) % 768;
    float iv = inv_[c], sh = shf[c];
    char4 kk = ((const char4*)k1)[u];
    float a = __fadd_rn(__fmul_rn(tab[kk.x + 127], iv), sh);
    float b = __fadd_rn(__fmul_rn(tab[kk.y + 127], iv), sh);
    float cc = __fadd_rn(__fmul_rn(tab[kk.z + 127], iv), sh);
    float d = __fadd_rn(__fmul_rn(tab[kk.w + 127], iv), sh);
    float4 o;
    o.x = fminf(fmaxf(rintf(a / s3), -127.f), 127.f) * s3;
    o.y = fminf(fmaxf(rintf(b / s3), -127.f), 127.f) * s3;
    o.z = fminf(fmaxf(rintf(cc / s3), -127.f), 127.f) * s3;
    o.w = fminf(fmaxf(rintf(d / s3), -127.f), 127.f) * s3;
    ((float4*)out)[u] = o;
  }
  if (blockIdx.x == 0 && threadIdx.x == 0) out[TOT] = s3;  // act_scale
}

extern "C" void kernel_launch(void* const* d_in, const int* in_sizes, int n_in,
                              void* d_out, int out_size, void* d_ws, size_t ws_size,
                              hipStream_t stream) {
  const float* x     = (const float*)d_in[0];
  const float* W     = (const float*)d_in[1];
  const float* bias  = (const float*)d_in[2];
  const float* gamma = (const float*)d_in[3];
  const float* beta  = (const float*)d_in[4];
  const float* rmean = (const float*)d_in[5];
  const float* rvar  = (const float*)d_in[6];
  float* out = (float*)d_out;
  char* ws = (char*)d_ws;

  signed char* aq  = (signed char*)(ws + OFF_AQ);
  signed char* wq  = (signed char*)(ws + OFF_WQ);
  float* wsc  = (float*)(ws + OFF_WSC);
  float* inv_ = (float*)(ws + OFF_INV);
  float* shf  = (float*)(ws + OFF_SHF);
  float* cmn  = (float*)(ws + OFF_CMN);
  float* cmx  = (float*)(ws + OFF_CMX);
  uint*  sc   = (uint*)(ws + OFF_SC);
  signed char* k1 = (signed char*)(ws + OFF_AQ);  // aliases aq (dead after GEMM)

  hipMemsetAsync(sc, 0, 16, stream);
  k_maxabs<<<2048, 256, 0, stream>>>(x, sc);
  k_wquant<<<768, 256, 0, stream>>>(W, gamma, beta, rmean, rvar, wq, wsc, inv_, shf);
  k_im2col<<<2048, 256, 0, stream>>>(x, sc, aq);
  k_gemm<<<1176, 256, 0, stream>>>(aq, wq, bias, wsc, sc, out);
  k_gelu_chan<<<768, 256, 0, stream>>>(out, sc, k1, cmn, cmx);
  k_scales<<<1, 256, 0, stream>>>(cmn, cmx, inv_, shf, sc);
  k_final<<<2048, 256, 0, stream>>>(k1, sc, inv_, shf, out);
}